// Round 6
// baseline (545.792 us; speedup 1.0000x reference)
//
#include <hip/hip_runtime.h>
#include <hip/hip_bf16.h>

typedef float f32x4 __attribute__((ext_vector_type(4)));
typedef int v8i __attribute__((ext_vector_type(8)));

#define AS3 __attribute__((address_space(3)))
#define AS1 __attribute__((address_space(1)))

// ---------------- fp32 -> fp8 e4m3 (OCP) conversion with x16 scale (q and t fused) ----------------
__global__ __launch_bounds__(256) void cvt_fp8_kernel(const float* __restrict__ q,
                                                      const float* __restrict__ t,
                                                      unsigned int* __restrict__ qd,
                                                      unsigned int* __restrict__ td) {
  int b = blockIdx.x;  // 8640 blocks: 4320 per matrix, 1024 float4 per block
  const float4* s4;
  unsigned int* dst;
  int base;
  if (b < 4320) { s4 = (const float4*)q; dst = qd; base = b * 1024; }
  else          { s4 = (const float4*)t; dst = td; base = (b - 4320) * 1024; }
#pragma unroll
  for (int i = 0; i < 4; ++i) {
    int j = base + i * 256 + threadIdx.x;
    float4 v = s4[j];
    int w = 0;
    w = __builtin_amdgcn_cvt_pk_fp8_f32(v.x * 16.f, v.y * 16.f, w, false);
    w = __builtin_amdgcn_cvt_pk_fp8_f32(v.z * 16.f, v.w * 16.f, w, true);
    dst[j] = w;
  }
}

// ---------------- fused GEMM (MX fp8, K=128) + max over p + mean over o -> f2f[512][512] ----------------
// R4 version (unchanged, proven): R1 loop + in-block o-mean epilogue.
__global__ __launch_bounds__(768) void gemm_cmax_kernel(const unsigned char* __restrict__ qf8,
                                                        const unsigned char* __restrict__ tf8,
                                                        float* __restrict__ f2f) {
  __shared__ __align__(16) char smem[147456];
  const int tid  = threadIdx.x;
  const int wv   = tid >> 6;
  const int lane = tid & 63;
  const int quad = lane >> 4;
  const int l16  = lane & 15;
  const int wrow = wv >> 1, wcol = wv & 1;
  const int x = blockIdx.x & 7, r = blockIdx.x >> 3;
  const int bi = (x >> 1) * 4 + (r & 3);
  const int bj = (x & 1) * 8 + (r >> 2);

  f32x4 acc[3][9];
#pragma unroll
  for (int a = 0; a < 3; ++a)
#pragma unroll
    for (int b = 0; b < 9; ++b) acc[a][b] = (f32x4){0.f, 0.f, 0.f, 0.f};

  const unsigned char* gptr[6];
#pragma unroll
  for (int i = 0; i < 6; ++i) {
    int s   = i * 768 + wv * 64 + lane;
    int mat = (s >= 2304);
    int sm  = s - mat * 2304;
    int row = sm >> 3, pc = sm & 7;
    int gc  = pc ^ (row & 7);
    const unsigned char* base = mat ? (tf8 + (size_t)(bj * 288 + row) * 3840)
                                    : (qf8 + (size_t)(bi * 288 + row) * 3840);
    gptr[i] = base + gc * 16;
  }

  int buf = 0;
#pragma unroll
  for (int i = 0; i < 6; ++i)
    __builtin_amdgcn_global_load_lds((const AS1 void*)(gptr[i]),
                                     (AS3 void*)(smem + (i * 768 + wv * 64) * 16), 16, 0, 0);

  const int arow0 = wrow * 48 + l16;
  const int bcol0 = wcol * 144 + l16;

  for (int kt = 0; kt < 30; ++kt) {
    __syncthreads();
    if (kt < 29) {
      int nb = buf ^ 1;
#pragma unroll
      for (int i = 0; i < 6; ++i)
        __builtin_amdgcn_global_load_lds((const AS1 void*)(gptr[i] + (kt + 1) * 128),
                                         (AS3 void*)(smem + nb * 73728 + (i * 768 + wv * 64) * 16),
                                         16, 0, 0);
    }
    const char* A = smem + buf * 73728;
    const char* B = A + 36864;

    v8i av[3];
#pragma unroll
    for (int sr = 0; sr < 3; ++sr) {
      int row = arow0 + sr * 16;
      int sw  = row & 7;
      int p0  = (quad * 2) ^ sw, p1 = (quad * 2 + 1) ^ sw;
      int4 lo = *(const int4*)(A + row * 128 + p0 * 16);
      int4 hi = *(const int4*)(A + row * 128 + p1 * 16);
      v8i v;
      v[0] = lo.x; v[1] = lo.y; v[2] = lo.z; v[3] = lo.w;
      v[4] = hi.x; v[5] = hi.y; v[6] = hi.z; v[7] = hi.w;
      av[sr] = v;
    }
#pragma unroll
    for (int c = 0; c < 9; ++c) {
      int col = bcol0 + c * 16;
      int sw  = col & 7;
      int p0  = (quad * 2) ^ sw, p1 = (quad * 2 + 1) ^ sw;
      int4 lo = *(const int4*)(B + col * 128 + p0 * 16);
      int4 hi = *(const int4*)(B + col * 128 + p1 * 16);
      v8i bv;
      bv[0] = lo.x; bv[1] = lo.y; bv[2] = lo.z; bv[3] = lo.w;
      bv[4] = hi.x; bv[5] = hi.y; bv[6] = hi.z; bv[7] = hi.w;
      acc[0][c] = __builtin_amdgcn_mfma_scale_f32_16x16x128_f8f6f4(
          av[0], bv, acc[0][c], 0, 0, 0, 0x7f7f7f7f, 0, 0x7f7f7f7f);
      acc[1][c] = __builtin_amdgcn_mfma_scale_f32_16x16x128_f8f6f4(
          av[1], bv, acc[1][c], 0, 0, 0, 0x7f7f7f7f, 0, 0x7f7f7f7f);
      acc[2][c] = __builtin_amdgcn_mfma_scale_f32_16x16x128_f8f6f4(
          av[2], bv, acc[2][c], 0, 0, 0, 0x7f7f7f7f, 0, 0x7f7f7f7f);
    }
    buf ^= 1;
  }

  __syncthreads();
  float* scr  = (float*)smem;                  // [16][288]
  float* mbuf = (float*)(smem + 18432);        // [288][33]
#pragma unroll
  for (int b = 0; b < 18; ++b) {
    const int bw = b / 3, bs = b - bw * 3;
    if (wrow == bw) {
#pragma unroll
      for (int c = 0; c < 9; ++c)
#pragma unroll
        for (int rr = 0; rr < 4; ++rr)
          scr[(quad * 4 + rr) * 288 + wcol * 144 + c * 16 + l16] = acc[bs][c][rr] * (1.f / 256.f);
    }
    __syncthreads();
    if (tid < 512) {
      int row = tid >> 5, jg = tid & 31;
      const float* p = scr + row * 288 + jg * 9;
      float m = p[0];
#pragma unroll
      for (int k = 1; k < 9; ++k) m = fmaxf(m, p[k]);
      mbuf[(b * 16 + row) * 33 + jg] = m;
    }
    __syncthreads();
  }
  for (int p = tid; p < 1024; p += 768) {
    int il = p >> 5, jg = p & 31;
    const float* mp = mbuf + (il * 9) * 33 + jg;
    float s = 0.f;
#pragma unroll
    for (int o = 0; o < 9; ++o) s += mp[o * 33];
    f2f[(size_t)(bi * 32 + il) * 512 + bj * 32 + jg] = s * (1.f / 9.f);
  }
}

// ---------------- manual grid barrier (release/acquire, device-scope) ----------------
// cooperative launch is graph-capture-hostile (R5 failure: kernel never ran);
// plain launch + counter barrier has identical semantics. Monotone counters,
// zeroed each replay by a hipMemsetAsync node before the launch.
__device__ __forceinline__ void grid_barrier(unsigned int* cnt, unsigned int nb) {
  __syncthreads();
  if (threadIdx.x == 0) {
    __threadfence();                         // release: agent-scope L2 writeback
    atomicAdd(cnt, 1u);
    while (atomicAdd(cnt, 0u) < nb) __builtin_amdgcn_s_sleep(8);
    __threadfence();                         // acquire: invalidate stale caches
  }
  __syncthreads();
}

// ---------------- megaconv: conv1+conv2+conv3+convf+final, ONE plain kernel ----------------
// 512 blocks x 256 threads; 4 grid barriers. LDS phases alias one 48384 B pool ->
// capacity 3 blocks/CU > 2 needed -> all 512 co-resident (no deadlock).
__global__ __launch_bounds__(256) void megaconv_kernel(const float* __restrict__ f2f,
                                                       const float* __restrict__ w1,
                                                       const float* __restrict__ b1,
                                                       const float* __restrict__ w2,
                                                       const float* __restrict__ b2,
                                                       const float* __restrict__ w3,
                                                       const float* __restrict__ b3,
                                                       const float* __restrict__ wf,
                                                       const float* __restrict__ bfp,
                                                       float* __restrict__ x1,
                                                       float* __restrict__ x2b,
                                                       float* __restrict__ x3,
                                                       float* __restrict__ rowm,
                                                       unsigned int* __restrict__ bars,
                                                       float* __restrict__ out) {
  __shared__ __align__(16) char pool[48384];
  const int b = blockIdx.x;
  const int tid = threadIdx.x;

  // ---- phase 1: conv1 (1->32ch, relu, 2x2 pool, 512^2 -> 256^2); 2 chg per block ----
  {
    float* wl = (float*)pool;                 // 320 floats
    float* tile1 = (float*)(pool + 1280);     // 34*36 floats
    int t = b & 255;
    int ty0 = (t >> 4) * 32, tx0 = (t & 15) * 32;
    int py = tid >> 4, px = tid & 15;

    for (int idx = tid; idx < 320; idx += 256)
      wl[idx] = (idx < 288) ? w1[idx] : b1[idx - 288];
    for (int idx = tid; idx < 34 * 34; idx += 256) {
      int rr = idx / 34, cc = idx % 34;
      int gy = ty0 + rr - 1, gx = tx0 + cc - 1;
      tile1[rr * 36 + cc] = ((unsigned)gy < 512u && (unsigned)gx < 512u) ? f2f[gy * 512 + gx] : 0.f;
    }
    __syncthreads();

    float win[4][4];
#pragma unroll
    for (int rr = 0; rr < 4; ++rr)
#pragma unroll
      for (int cc = 0; cc < 4; ++cc)
        win[rr][cc] = tile1[(2 * py + rr) * 36 + 2 * px + cc];

    int gy2 = (t >> 4) * 16 + py, gx2 = (t & 15) * 16 + px;
#pragma unroll 1
    for (int g = 0; g < 2; ++g) {
      int ch0 = ((b >> 8) + g * 2) * 8;
      for (int ch = ch0; ch < ch0 + 8; ++ch) {
        float w[9];
#pragma unroll
        for (int k = 0; k < 9; ++k) w[k] = wl[ch * 9 + k];
        float m = -INFINITY;
#pragma unroll
        for (int a = 0; a < 2; ++a)
#pragma unroll
          for (int bb = 0; bb < 2; ++bb) {
            float s = 0.f;
#pragma unroll
            for (int ky = 0; ky < 3; ++ky)
#pragma unroll
              for (int kx = 0; kx < 3; ++kx) s += win[a + ky][bb + kx] * w[ky * 3 + kx];
            m = fmaxf(m, s);
          }
        x1[ch * 65536 + gy2 * 256 + gx2] = fmaxf(m + wl[288 + ch], 0.f);
      }
    }
  }
  grid_barrier(bars + 0, 512);

  // ---- phase 2: conv2 (32->64ch, relu, 2x2 pool, 256^2 -> 128^2) ----
  {
    float* wlds = (float*)pool;               // 6144 B
    float* tile = (float*)(pool + 6144);      // 42240 B
    const int stripe = b & 31, cog = b >> 5;
    const int X = tid;
    const int Y0 = stripe * 8;

    for (int idx = tid; idx < 1152; idx += 256) {
      int co = idx / 288, rem = idx % 288, ci = rem / 9, k = rem % 9;
      wlds[(ci * 4 + co) * 12 + k] = w2[((cog * 4 + co) * 32 + ci) * 9 + k];
    }
    if (tid < 80) {
      int bu = tid / 40, rem = tid % 40, pl = rem / 20, r2 = rem % 20;
      int rr = r2 >> 1, side = r2 & 1;
      tile[bu * 5280 + pl * 2640 + rr * 264 + (side ? 260 : 3)] = 0.f;
    }
    int gof[5], lof[5];
#pragma unroll
    for (int i = 0; i < 5; ++i) {
      int idx = tid + i * 256;
      int rw = idx >> 6, c4 = idx & 63;
      int pl = (rw >= 10), rr = rw - pl * 10;
      int gy = Y0 + rr - 1;
      lof[i] = pl * 2640 + rr * 264 + 4 + c4 * 4;
      gof[i] = ((unsigned)gy < 256u) ? (pl * 65536 + gy * 256 + c4 * 4) : -1;
    }
#pragma unroll
    for (int i = 0; i < 5; ++i) {
      float4 v = (gof[i] >= 0) ? *(const float4*)(x1 + gof[i]) : (float4){0, 0, 0, 0};
      *(float4*)&tile[lof[i]] = v;
    }
    __syncthreads();

    float acc[8][4];
#pragma unroll
    for (int y = 0; y < 8; ++y)
#pragma unroll
      for (int co = 0; co < 4; ++co) acc[y][co] = 0.f;

#pragma unroll 1
    for (int cb = 0; cb < 16; ++cb) {
      int buf = cb & 1;
      float4 pf[5];
      if (cb < 15) {
#pragma unroll
        for (int i = 0; i < 5; ++i)
          pf[i] = (gof[i] >= 0) ? *(const float4*)(x1 + gof[i] + (cb + 1) * 131072)
                                : (float4){0, 0, 0, 0};
      }
      const float* tb = tile + buf * 5280;
#pragma unroll
      for (int pl = 0; pl < 2; ++pl) {
        const float* tp = tb + pl * 2640;
        int ci = cb * 2 + pl;
        float w[4][9];
#pragma unroll
        for (int co = 0; co < 4; ++co) {
          const float* wp = &wlds[(ci * 4 + co) * 12];
          float4 w0 = *(const float4*)wp;
          float4 w1v = *(const float4*)(wp + 4);
          w[co][0] = w0.x; w[co][1] = w0.y; w[co][2] = w0.z; w[co][3] = w0.w;
          w[co][4] = w1v.x; w[co][5] = w1v.y; w[co][6] = w1v.z; w[co][7] = w1v.w;
          w[co][8] = wp[8];
        }
        float r0[3], r1[3], r2[3];
        const float* p0 = tp + X + 3;
        r0[0] = p0[0]; r0[1] = p0[1]; r0[2] = p0[2];
        const float* p1 = tp + 264 + X + 3;
        r1[0] = p1[0]; r1[1] = p1[1]; r1[2] = p1[2];
#pragma unroll
        for (int y = 0; y < 8; ++y) {
          const float* p2 = tp + (y + 2) * 264 + X + 3;
          r2[0] = p2[0]; r2[1] = p2[1]; r2[2] = p2[2];
#pragma unroll
          for (int co = 0; co < 4; ++co)
            acc[y][co] += r0[0] * w[co][0] + r0[1] * w[co][1] + r0[2] * w[co][2]
                        + r1[0] * w[co][3] + r1[1] * w[co][4] + r1[2] * w[co][5]
                        + r2[0] * w[co][6] + r2[1] * w[co][7] + r2[2] * w[co][8];
          r0[0] = r1[0]; r0[1] = r1[1]; r0[2] = r1[2];
          r1[0] = r2[0]; r1[1] = r2[1]; r1[2] = r2[2];
        }
      }
      if (cb < 15) {
#pragma unroll
        for (int i = 0; i < 5; ++i)
          *(float4*)&tile[(buf ^ 1) * 5280 + lof[i]] = pf[i];
      }
      __syncthreads();
    }

    int x2 = X >> 1;
#pragma unroll
    for (int co = 0; co < 4; ++co) {
      float bias = b2[cog * 4 + co];
#pragma unroll
      for (int y2 = 0; y2 < 4; ++y2) {
        float v = fmaxf(acc[2 * y2][co], acc[2 * y2 + 1][co]);
        v = fmaxf(v + bias, 0.f);
        float o = fmaxf(v, __shfl_xor(v, 1, 64));
        if ((X & 1) == 0)
          x2b[(cog * 4 + co) * 16384 + (stripe * 4 + y2) * 128 + x2] = o;
      }
    }
  }
  grid_barrier(bars + 1, 512);

  // ---- phase 3: conv3 (64->128ch, relu, 128^2) ----
  {
    float* wlds = (float*)pool;               // 6144 B
    float* tile = (float*)(pool + 6144);      // 39168 B
    const int stripe = b & 7, cog = b >> 3;
    const int X = tid & 127, yh = tid >> 7;
    const int Y0 = stripe * 16;

    for (int idx = tid; idx < 1152; idx += 256) {
      int co = idx / 576, rem = idx % 576, ci = rem / 9, k = rem % 9;
      wlds[(ci * 2 + co) * 12 + k] = w3[((cog * 2 + co) * 64 + ci) * 9 + k];
    }
    if (tid < 144) {
      int bu = tid / 72, rem = tid % 72, pl = rem / 36, r2 = rem % 36;
      int rr = r2 >> 1, side = r2 & 1;
      tile[bu * 4896 + pl * 2448 + rr * 136 + (side ? 132 : 3)] = 0.f;
    }
    int gof[5], lof[5];
#pragma unroll
    for (int i = 0; i < 5; ++i) {
      int idx = tid + i * 256;
      if (idx < 1152) {
        int rw = idx >> 5, c4 = idx & 31;
        int pl = (rw >= 18), rr = rw - pl * 18;
        int gy = Y0 + rr - 1;
        lof[i] = pl * 2448 + rr * 136 + 4 + c4 * 4;
        gof[i] = ((unsigned)gy < 128u) ? (pl * 16384 + gy * 128 + c4 * 4) : -1;
      } else { lof[i] = -1; gof[i] = -1; }
    }
#pragma unroll
    for (int i = 0; i < 5; ++i)
      if (lof[i] >= 0) {
        float4 v = (gof[i] >= 0) ? *(const float4*)(x2b + gof[i]) : (float4){0, 0, 0, 0};
        *(float4*)&tile[lof[i]] = v;
      }
    __syncthreads();

    float acc[8][2];
#pragma unroll
    for (int y = 0; y < 8; ++y)
#pragma unroll
      for (int co = 0; co < 2; ++co) acc[y][co] = 0.f;

#pragma unroll 1
    for (int cb = 0; cb < 32; ++cb) {
      int buf = cb & 1;
      float4 pf[5];
      if (cb < 31) {
#pragma unroll
        for (int i = 0; i < 5; ++i)
          pf[i] = (gof[i] >= 0) ? *(const float4*)(x2b + gof[i] + (cb + 1) * 32768)
                                : (float4){0, 0, 0, 0};
      }
      const float* tb = tile + buf * 4896;
#pragma unroll
      for (int pl = 0; pl < 2; ++pl) {
        const float* tp = tb + pl * 2448;
        int ci = cb * 2 + pl;
        float w[2][9];
#pragma unroll
        for (int co = 0; co < 2; ++co) {
          const float* wp = &wlds[(ci * 2 + co) * 12];
          float4 w0 = *(const float4*)wp;
          float4 w1v = *(const float4*)(wp + 4);
          w[co][0] = w0.x; w[co][1] = w0.y; w[co][2] = w0.z; w[co][3] = w0.w;
          w[co][4] = w1v.x; w[co][5] = w1v.y; w[co][6] = w1v.z; w[co][7] = w1v.w;
          w[co][8] = wp[8];
        }
        float r0[3], r1[3], r2[3];
        const float* p0 = tp + (yh * 8) * 136 + X + 3;
        r0[0] = p0[0]; r0[1] = p0[1]; r0[2] = p0[2];
        const float* p1 = tp + (yh * 8 + 1) * 136 + X + 3;
        r1[0] = p1[0]; r1[1] = p1[1]; r1[2] = p1[2];
#pragma unroll
        for (int y = 0; y < 8; ++y) {
          const float* p2 = tp + (yh * 8 + y + 2) * 136 + X + 3;
          r2[0] = p2[0]; r2[1] = p2[1]; r2[2] = p2[2];
#pragma unroll
          for (int co = 0; co < 2; ++co)
            acc[y][co] += r0[0] * w[co][0] + r0[1] * w[co][1] + r0[2] * w[co][2]
                        + r1[0] * w[co][3] + r1[1] * w[co][4] + r1[2] * w[co][5]
                        + r2[0] * w[co][6] + r2[1] * w[co][7] + r2[2] * w[co][8];
          r0[0] = r1[0]; r0[1] = r1[1]; r0[2] = r1[2];
          r1[0] = r2[0]; r1[1] = r2[1]; r1[2] = r2[2];
        }
      }
      if (cb < 31) {
#pragma unroll
        for (int i = 0; i < 5; ++i)
          if (lof[i] >= 0) *(float4*)&tile[(buf ^ 1) * 4896 + lof[i]] = pf[i];
      }
      __syncthreads();
    }

#pragma unroll
    for (int co = 0; co < 2; ++co) {
      float bias = b3[cog * 2 + co];
      float* op = x3 + (cog * 2 + co) * 16384 + (Y0 + yh * 8) * 128 + X;
#pragma unroll
      for (int y = 0; y < 8; ++y)
        op[y * 128] = fmaxf(acc[y][co] + bias, 0.f);
    }
  }
  grid_barrier(bars + 2, 512);

  // ---- phase 4: convf (1x1 conv 128->1 + bias + clip + rowmax); blocks 0..127 ----
  if (b < 128) {
    float* fpart = (float*)pool;  // 256 floats
    int y = b;
    int xx = tid & 127, pt = tid >> 7;  // 2 partials of 64 ci
    float acc = 0.f;
    const float* ip = x3 + y * 128 + xx;
    for (int ci = pt * 64; ci < pt * 64 + 64; ++ci) acc += ip[ci * 16384] * wf[ci];
    fpart[tid] = acc;
    __syncthreads();
    if (tid < 128) {
      float s = fpart[tid] + fpart[tid + 128] + bfp[0];
      fpart[tid] = fminf(fmaxf(s, -1.f), 1.f);
    }
    __syncthreads();
    if (tid < 64) {
      float m = fmaxf(fpart[tid], fpart[tid + 64]);
      for (int off = 32; off; off >>= 1) m = fmaxf(m, __shfl_down(m, off, 64));
      if (tid == 0) rowm[y] = m;
    }
  }
  grid_barrier(bars + 3, 512);

  // ---- phase 5: final mean over 128 rows -> scalar; block 0 ----
  if (b == 0) {
    float* red = (float*)pool;
    float v = (tid < 128) ? rowm[tid] : 0.f;
    for (int off = 32; off; off >>= 1) v += __shfl_down(v, off, 64);
    if (tid < 128 && (tid & 63) == 0) red[tid >> 6] = v;
    __syncthreads();
    if (tid == 0) out[0] = (red[0] + red[1]) * (1.f / 128.f);
  }
}

extern "C" void kernel_launch(void* const* d_in, const int* in_sizes, int n_in,
                              void* d_out, int out_size, void* d_ws, size_t ws_size,
                              hipStream_t stream) {
  const float* q  = (const float*)d_in[0];
  const float* t  = (const float*)d_in[1];
  const float* w1 = (const float*)d_in[2];
  const float* b1 = (const float*)d_in[3];
  const float* w2 = (const float*)d_in[4];
  const float* b2 = (const float*)d_in[5];
  const float* w3 = (const float*)d_in[6];
  const float* b3 = (const float*)d_in[7];
  const float* wf = (const float*)d_in[8];
  const float* bf = (const float*)d_in[9];
  float* out = (float*)d_out;
  char* ws = (char*)d_ws;

  unsigned char* qf8 = (unsigned char*)(ws + 0);          // 17,694,720
  unsigned char* tf8 = (unsigned char*)(ws + 17694720);   // 17,694,720
  float* f2f  = (float*)(ws + 44826624);                  // 512x512
  float* x1   = (float*)(ws + 45875200);                  // 32x256x256
  float* x2b  = (float*)(ws + 54263808);                  // 64x128x128
  float* x3   = (float*)(ws + 58458112);                  // 128x128x128
  float* rowm = (float*)(ws + 66846720);                  // 128 floats
  unsigned int* bars = (unsigned int*)(ws + 66847232);    // 4 barrier counters

  hipMemsetAsync(bars, 0, 64, stream);  // re-zero each graph replay (capturable node)
  cvt_fp8_kernel<<<8640, 256, 0, stream>>>(q, t, (unsigned int*)qf8, (unsigned int*)tf8);
  gemm_cmax_kernel<<<256, 768, 0, stream>>>(qf8, tf8, f2f);
  megaconv_kernel<<<512, 256, 0, stream>>>(f2f, w1, b1, w2, b2, w3, b3, wf, bf,
                                           x1, x2b, x3, rowm, bars, out);
}

// Round 8
// 462.184 us; speedup vs baseline: 1.1809x; 1.1809x over previous
//
#include <hip/hip_runtime.h>
#include <hip/hip_bf16.h>

typedef float f32x4 __attribute__((ext_vector_type(4)));
typedef int v8i __attribute__((ext_vector_type(8)));

#define AS3 __attribute__((address_space(3)))
#define AS1 __attribute__((address_space(1)))

// ---------------- fp32 -> fp8 e4m3 (OCP) conversion with x16 scale (q and t fused) ----------------
// R4-proven. Lane-contiguous: lane i reads float4 i (16B/lane), writes packed uint (4B/lane).
__global__ __launch_bounds__(256) void cvt_fp8_kernel(const float* __restrict__ q,
                                                      const float* __restrict__ t,
                                                      unsigned int* __restrict__ qd,
                                                      unsigned int* __restrict__ td) {
  int b = blockIdx.x;  // 8640 blocks: 4320 per matrix, 1024 float4 per block
  const float4* s4;
  unsigned int* dst;
  int base;
  if (b < 4320) { s4 = (const float4*)q; dst = qd; base = b * 1024; }
  else          { s4 = (const float4*)t; dst = td; base = (b - 4320) * 1024; }
#pragma unroll
  for (int i = 0; i < 4; ++i) {
    int j = base + i * 256 + threadIdx.x;
    float4 v = s4[j];
    int w = 0;
    w = __builtin_amdgcn_cvt_pk_fp8_f32(v.x * 16.f, v.y * 16.f, w, false);
    w = __builtin_amdgcn_cvt_pk_fp8_f32(v.z * 16.f, v.w * 16.f, w, true);
    dst[j] = w;
  }
}

// ---------------- fused GEMM (MX fp8, K=128) + max over p + mean over o -> f2f[512][512] ----------------
// R4 version (unchanged, proven 122.8 us): R1 loop + in-block o-mean epilogue.
__global__ __launch_bounds__(768) void gemm_cmax_kernel(const unsigned char* __restrict__ qf8,
                                                        const unsigned char* __restrict__ tf8,
                                                        float* __restrict__ f2f) {
  __shared__ __align__(16) char smem[147456];
  const int tid  = threadIdx.x;
  const int wv   = tid >> 6;
  const int lane = tid & 63;
  const int quad = lane >> 4;
  const int l16  = lane & 15;
  const int wrow = wv >> 1, wcol = wv & 1;
  const int x = blockIdx.x & 7, r = blockIdx.x >> 3;
  const int bi = (x >> 1) * 4 + (r & 3);
  const int bj = (x & 1) * 8 + (r >> 2);

  f32x4 acc[3][9];
#pragma unroll
  for (int a = 0; a < 3; ++a)
#pragma unroll
    for (int b = 0; b < 9; ++b) acc[a][b] = (f32x4){0.f, 0.f, 0.f, 0.f};

  const unsigned char* gptr[6];
#pragma unroll
  for (int i = 0; i < 6; ++i) {
    int s   = i * 768 + wv * 64 + lane;
    int mat = (s >= 2304);
    int sm  = s - mat * 2304;
    int row = sm >> 3, pc = sm & 7;
    int gc  = pc ^ (row & 7);
    const unsigned char* base = mat ? (tf8 + (size_t)(bj * 288 + row) * 3840)
                                    : (qf8 + (size_t)(bi * 288 + row) * 3840);
    gptr[i] = base + gc * 16;
  }

  int buf = 0;
#pragma unroll
  for (int i = 0; i < 6; ++i)
    __builtin_amdgcn_global_load_lds((const AS1 void*)(gptr[i]),
                                     (AS3 void*)(smem + (i * 768 + wv * 64) * 16), 16, 0, 0);

  const int arow0 = wrow * 48 + l16;
  const int bcol0 = wcol * 144 + l16;

  for (int kt = 0; kt < 30; ++kt) {
    __syncthreads();
    if (kt < 29) {
      int nb = buf ^ 1;
#pragma unroll
      for (int i = 0; i < 6; ++i)
        __builtin_amdgcn_global_load_lds((const AS1 void*)(gptr[i] + (kt + 1) * 128),
                                         (AS3 void*)(smem + nb * 73728 + (i * 768 + wv * 64) * 16),
                                         16, 0, 0);
    }
    const char* A = smem + buf * 73728;
    const char* B = A + 36864;

    v8i av[3];
#pragma unroll
    for (int sr = 0; sr < 3; ++sr) {
      int row = arow0 + sr * 16;
      int sw  = row & 7;
      int p0  = (quad * 2) ^ sw, p1 = (quad * 2 + 1) ^ sw;
      int4 lo = *(const int4*)(A + row * 128 + p0 * 16);
      int4 hi = *(const int4*)(A + row * 128 + p1 * 16);
      v8i v;
      v[0] = lo.x; v[1] = lo.y; v[2] = lo.z; v[3] = lo.w;
      v[4] = hi.x; v[5] = hi.y; v[6] = hi.z; v[7] = hi.w;
      av[sr] = v;
    }
#pragma unroll
    for (int c = 0; c < 9; ++c) {
      int col = bcol0 + c * 16;
      int sw  = col & 7;
      int p0  = (quad * 2) ^ sw, p1 = (quad * 2 + 1) ^ sw;
      int4 lo = *(const int4*)(B + col * 128 + p0 * 16);
      int4 hi = *(const int4*)(B + col * 128 + p1 * 16);
      v8i bv;
      bv[0] = lo.x; bv[1] = lo.y; bv[2] = lo.z; bv[3] = lo.w;
      bv[4] = hi.x; bv[5] = hi.y; bv[6] = hi.z; bv[7] = hi.w;
      acc[0][c] = __builtin_amdgcn_mfma_scale_f32_16x16x128_f8f6f4(
          av[0], bv, acc[0][c], 0, 0, 0, 0x7f7f7f7f, 0, 0x7f7f7f7f);
      acc[1][c] = __builtin_amdgcn_mfma_scale_f32_16x16x128_f8f6f4(
          av[1], bv, acc[1][c], 0, 0, 0, 0x7f7f7f7f, 0, 0x7f7f7f7f);
      acc[2][c] = __builtin_amdgcn_mfma_scale_f32_16x16x128_f8f6f4(
          av[2], bv, acc[2][c], 0, 0, 0, 0x7f7f7f7f, 0, 0x7f7f7f7f);
    }
    buf ^= 1;
  }

  __syncthreads();
  float* scr  = (float*)smem;                  // [16][288]
  float* mbuf = (float*)(smem + 18432);        // [288][33]
#pragma unroll
  for (int b = 0; b < 18; ++b) {
    const int bw = b / 3, bs = b - bw * 3;
    if (wrow == bw) {
#pragma unroll
      for (int c = 0; c < 9; ++c)
#pragma unroll
        for (int rr = 0; rr < 4; ++rr)
          scr[(quad * 4 + rr) * 288 + wcol * 144 + c * 16 + l16] = acc[bs][c][rr] * (1.f / 256.f);
    }
    __syncthreads();
    if (tid < 512) {
      int row = tid >> 5, jg = tid & 31;
      const float* p = scr + row * 288 + jg * 9;
      float m = p[0];
#pragma unroll
      for (int k = 1; k < 9; ++k) m = fmaxf(m, p[k]);
      mbuf[(b * 16 + row) * 33 + jg] = m;
    }
    __syncthreads();
  }
  for (int p = tid; p < 1024; p += 768) {
    int il = p >> 5, jg = p & 31;
    const float* mp = mbuf + (il * 9) * 33 + jg;
    float s = 0.f;
#pragma unroll
    for (int o = 0; o < 9; ++o) s += mp[o * 33];
    f2f[(size_t)(bi * 32 + il) * 512 + bj * 32 + jg] = s * (1.f / 9.f);
  }
}

// ---------------- conv1: 1->32ch 3x3 same + relu + 2x2 maxpool, 512^2 -> 256^2 ----------------
// R4-proven (1024 blocks, 4 chg x 8 ch).
__global__ __launch_bounds__(256) void conv1_kernel(const float* __restrict__ in,
                                                    const float* __restrict__ w1,
                                                    const float* __restrict__ b1,
                                                    float* __restrict__ out) {
  __shared__ float tile[34 * 36];
  __shared__ float wl[320];
  int t = blockIdx.x & 255;
  int chg = blockIdx.x >> 8;
  int ty0 = (t >> 4) * 32, tx0 = (t & 15) * 32;
  int py = threadIdx.x >> 4, px = threadIdx.x & 15;

  for (int idx = threadIdx.x; idx < 320; idx += 256)
    wl[idx] = (idx < 288) ? w1[idx] : b1[idx - 288];
  for (int idx = threadIdx.x; idx < 34 * 34; idx += 256) {
    int r = idx / 34, c = idx % 34;
    int gy = ty0 + r - 1, gx = tx0 + c - 1;
    tile[r * 36 + c] = ((unsigned)gy < 512u && (unsigned)gx < 512u) ? in[gy * 512 + gx] : 0.f;
  }
  __syncthreads();

  float win[4][4];
#pragma unroll
  for (int r = 0; r < 4; ++r)
#pragma unroll
    for (int c = 0; c < 4; ++c)
      win[r][c] = tile[(2 * py + r) * 36 + 2 * px + c];

  int gy2 = (t >> 4) * 16 + py, gx2 = (t & 15) * 16 + px;
  int ch0 = chg * 8;
  for (int ch = ch0; ch < ch0 + 8; ++ch) {
    float w[9];
#pragma unroll
    for (int k = 0; k < 9; ++k) w[k] = wl[ch * 9 + k];
    float m = -INFINITY;
#pragma unroll
    for (int a = 0; a < 2; ++a)
#pragma unroll
      for (int b = 0; b < 2; ++b) {
        float s = 0.f;
#pragma unroll
        for (int ky = 0; ky < 3; ++ky)
#pragma unroll
          for (int kx = 0; kx < 3; ++kx) s += win[a + ky][b + kx] * w[ky * 3 + kx];
        m = fmaxf(m, s);
      }
    out[ch * 65536 + gy2 * 256 + gx2] = fmaxf(m + wl[288 + ch], 0.f);
  }
}

// ---------------- conv2: 32->64ch 3x3 same + relu + 2x2 maxpool, 256^2 -> 128^2 ----------------
// R4-proven (512 blocks = 32 stripes x 16 cog).
__global__ __launch_bounds__(256) void conv2_kernel(const float* __restrict__ in,
                                                    const float* __restrict__ w2,
                                                    const float* __restrict__ b2,
                                                    float* __restrict__ out) {
  __shared__ __align__(16) float wlds[32 * 4 * 12];        // 6144 B
  __shared__ __align__(16) float tile[2 * 2 * 10 * 264];   // 42240 B
  const int tid = threadIdx.x;
  const int stripe = blockIdx.x & 31, cog = blockIdx.x >> 5;
  const int X = tid;
  const int Y0 = stripe * 8;

  for (int idx = tid; idx < 1152; idx += 256) {
    int co = idx / 288, rem = idx % 288, ci = rem / 9, k = rem % 9;
    wlds[(ci * 4 + co) * 12 + k] = w2[((cog * 4 + co) * 32 + ci) * 9 + k];
  }
  if (tid < 80) {
    int bu = tid / 40, rem = tid % 40, pl = rem / 20, r2 = rem % 20;
    int rr = r2 >> 1, side = r2 & 1;
    tile[bu * 5280 + pl * 2640 + rr * 264 + (side ? 260 : 3)] = 0.f;
  }
  int gof[5], lof[5];
#pragma unroll
  for (int i = 0; i < 5; ++i) {
    int idx = tid + i * 256;
    int rw = idx >> 6, c4 = idx & 63;
    int pl = (rw >= 10), rr = rw - pl * 10;
    int gy = Y0 + rr - 1;
    lof[i] = pl * 2640 + rr * 264 + 4 + c4 * 4;
    gof[i] = ((unsigned)gy < 256u) ? (pl * 65536 + gy * 256 + c4 * 4) : -1;
  }
#pragma unroll
  for (int i = 0; i < 5; ++i) {
    float4 v = (gof[i] >= 0) ? *(const float4*)(in + gof[i]) : (float4){0, 0, 0, 0};
    *(float4*)&tile[lof[i]] = v;
  }
  __syncthreads();

  float acc[8][4];
#pragma unroll
  for (int y = 0; y < 8; ++y)
#pragma unroll
    for (int co = 0; co < 4; ++co) acc[y][co] = 0.f;

#pragma unroll 1
  for (int cb = 0; cb < 16; ++cb) {
    int buf = cb & 1;
    float4 pf[5];
    if (cb < 15) {
#pragma unroll
      for (int i = 0; i < 5; ++i)
        pf[i] = (gof[i] >= 0) ? *(const float4*)(in + gof[i] + (cb + 1) * 131072)
                              : (float4){0, 0, 0, 0};
    }
    const float* tb = tile + buf * 5280;
#pragma unroll
    for (int pl = 0; pl < 2; ++pl) {
      const float* tp = tb + pl * 2640;
      int ci = cb * 2 + pl;
      float w[4][9];
#pragma unroll
      for (int co = 0; co < 4; ++co) {
        const float* wp = &wlds[(ci * 4 + co) * 12];
        float4 w0 = *(const float4*)wp;
        float4 w1v = *(const float4*)(wp + 4);
        w[co][0] = w0.x; w[co][1] = w0.y; w[co][2] = w0.z; w[co][3] = w0.w;
        w[co][4] = w1v.x; w[co][5] = w1v.y; w[co][6] = w1v.z; w[co][7] = w1v.w;
        w[co][8] = wp[8];
      }
      float r0[3], r1[3], r2[3];
      const float* p0 = tp + X + 3;
      r0[0] = p0[0]; r0[1] = p0[1]; r0[2] = p0[2];
      const float* p1 = tp + 264 + X + 3;
      r1[0] = p1[0]; r1[1] = p1[1]; r1[2] = p1[2];
#pragma unroll
      for (int y = 0; y < 8; ++y) {
        const float* p2 = tp + (y + 2) * 264 + X + 3;
        r2[0] = p2[0]; r2[1] = p2[1]; r2[2] = p2[2];
#pragma unroll
        for (int co = 0; co < 4; ++co)
          acc[y][co] += r0[0] * w[co][0] + r0[1] * w[co][1] + r0[2] * w[co][2]
                      + r1[0] * w[co][3] + r1[1] * w[co][4] + r1[2] * w[co][5]
                      + r2[0] * w[co][6] + r2[1] * w[co][7] + r2[2] * w[co][8];
        r0[0] = r1[0]; r0[1] = r1[1]; r0[2] = r1[2];
        r1[0] = r2[0]; r1[1] = r2[1]; r1[2] = r2[2];
      }
    }
    if (cb < 15) {
#pragma unroll
      for (int i = 0; i < 5; ++i)
        *(float4*)&tile[(buf ^ 1) * 5280 + lof[i]] = pf[i];
    }
    __syncthreads();
  }

  int x2 = X >> 1;
#pragma unroll
  for (int co = 0; co < 4; ++co) {
    float bias = b2[cog * 4 + co];
#pragma unroll
    for (int y2 = 0; y2 < 4; ++y2) {
      float v = fmaxf(acc[2 * y2][co], acc[2 * y2 + 1][co]);
      v = fmaxf(v + bias, 0.f);
      float o = fmaxf(v, __shfl_xor(v, 1, 64));
      if ((X & 1) == 0)
        out[(cog * 4 + co) * 16384 + (stripe * 4 + y2) * 128 + x2] = o;
    }
  }
}

// ---------------- conv3 + convf + final, fused (saves 2 kernel boundaries ~= 40 us) ----------------
// conv3 R4-proven body; then ONE load-polling grid barrier (arrival = single fetch_add per
// block; spin = atomic LOADS + s_sleep, no RMW storm -- R6's RMW-poll barrier cost ~50us);
// blocks 0..127 run convf; last convf block runs final.
// Deadlock-safe: 45.3 KB LDS -> 3 blocks/CU capacity > 2 needed -> all 512 co-resident.
__global__ __launch_bounds__(256) void conv3f_kernel(const float* __restrict__ in,
                                                     const float* __restrict__ w3,
                                                     const float* __restrict__ b3,
                                                     const float* __restrict__ wf,
                                                     const float* __restrict__ bfp,
                                                     float* __restrict__ x3,
                                                     float* __restrict__ rowm,
                                                     unsigned int* __restrict__ bars,
                                                     float* __restrict__ out) {
  __shared__ __align__(16) float wlds[64 * 2 * 12];       // 6144 B (reused as fpart/red later)
  __shared__ __align__(16) float tile[2 * 2 * 18 * 136];  // 39168 B
  __shared__ unsigned int lastf;
  const int b = blockIdx.x;
  const int tid = threadIdx.x;
  const int stripe = b & 7, cog = b >> 3;
  const int X = tid & 127, yh = tid >> 7;
  const int Y0 = stripe * 16;

  for (int idx = tid; idx < 1152; idx += 256) {
    int co = idx / 576, rem = idx % 576, ci = rem / 9, k = rem % 9;
    wlds[(ci * 2 + co) * 12 + k] = w3[((cog * 2 + co) * 64 + ci) * 9 + k];
  }
  if (tid < 144) {
    int bu = tid / 72, rem = tid % 72, pl = rem / 36, r2 = rem % 36;
    int rr = r2 >> 1, side = r2 & 1;
    tile[bu * 4896 + pl * 2448 + rr * 136 + (side ? 132 : 3)] = 0.f;
  }
  int gof[5], lof[5];
#pragma unroll
  for (int i = 0; i < 5; ++i) {
    int idx = tid + i * 256;
    if (idx < 1152) {
      int rw = idx >> 5, c4 = idx & 31;
      int pl = (rw >= 18), rr = rw - pl * 18;
      int gy = Y0 + rr - 1;
      lof[i] = pl * 2448 + rr * 136 + 4 + c4 * 4;
      gof[i] = ((unsigned)gy < 128u) ? (pl * 16384 + gy * 128 + c4 * 4) : -1;
    } else { lof[i] = -1; gof[i] = -1; }
  }
#pragma unroll
  for (int i = 0; i < 5; ++i)
    if (lof[i] >= 0) {
      float4 v = (gof[i] >= 0) ? *(const float4*)(in + gof[i]) : (float4){0, 0, 0, 0};
      *(float4*)&tile[lof[i]] = v;
    }
  __syncthreads();

  float acc[8][2];
#pragma unroll
  for (int y = 0; y < 8; ++y)
#pragma unroll
    for (int co = 0; co < 2; ++co) acc[y][co] = 0.f;

#pragma unroll 1
  for (int cb = 0; cb < 32; ++cb) {
    int buf = cb & 1;
    float4 pf[5];
    if (cb < 31) {
#pragma unroll
      for (int i = 0; i < 5; ++i)
        pf[i] = (gof[i] >= 0) ? *(const float4*)(in + gof[i] + (cb + 1) * 32768)
                              : (float4){0, 0, 0, 0};
    }
    const float* tb = tile + buf * 4896;
#pragma unroll
    for (int pl = 0; pl < 2; ++pl) {
      const float* tp = tb + pl * 2448;
      int ci = cb * 2 + pl;
      float w[2][9];
#pragma unroll
      for (int co = 0; co < 2; ++co) {
        const float* wp = &wlds[(ci * 2 + co) * 12];
        float4 w0 = *(const float4*)wp;
        float4 w1v = *(const float4*)(wp + 4);
        w[co][0] = w0.x; w[co][1] = w0.y; w[co][2] = w0.z; w[co][3] = w0.w;
        w[co][4] = w1v.x; w[co][5] = w1v.y; w[co][6] = w1v.z; w[co][7] = w1v.w;
        w[co][8] = wp[8];
      }
      float r0[3], r1[3], r2[3];
      const float* p0 = tp + (yh * 8) * 136 + X + 3;
      r0[0] = p0[0]; r0[1] = p0[1]; r0[2] = p0[2];
      const float* p1 = tp + (yh * 8 + 1) * 136 + X + 3;
      r1[0] = p1[0]; r1[1] = p1[1]; r1[2] = p1[2];
#pragma unroll
      for (int y = 0; y < 8; ++y) {
        const float* p2 = tp + (yh * 8 + y + 2) * 136 + X + 3;
        r2[0] = p2[0]; r2[1] = p2[1]; r2[2] = p2[2];
#pragma unroll
        for (int co = 0; co < 2; ++co)
          acc[y][co] += r0[0] * w[co][0] + r0[1] * w[co][1] + r0[2] * w[co][2]
                      + r1[0] * w[co][3] + r1[1] * w[co][4] + r1[2] * w[co][5]
                      + r2[0] * w[co][6] + r2[1] * w[co][7] + r2[2] * w[co][8];
        r0[0] = r1[0]; r0[1] = r1[1]; r0[2] = r1[2];
        r1[0] = r2[0]; r1[1] = r2[1]; r1[2] = r2[2];
      }
    }
    if (cb < 31) {
#pragma unroll
      for (int i = 0; i < 5; ++i)
        if (lof[i] >= 0) *(float4*)&tile[(buf ^ 1) * 4896 + lof[i]] = pf[i];
    }
    __syncthreads();
  }

#pragma unroll
  for (int co = 0; co < 2; ++co) {
    float bias = b3[cog * 2 + co];
    float* op = x3 + (cog * 2 + co) * 16384 + (Y0 + yh * 8) * 128 + X;
#pragma unroll
    for (int y = 0; y < 8; ++y)
      op[y * 128] = fmaxf(acc[y][co] + bias, 0.f);
  }

  // ---- load-polling grid barrier: all x3 writes visible ----
  __syncthreads();
  if (tid == 0) {
    __threadfence();  // release: drain x3 stores to L2 (device scope)
    __hip_atomic_fetch_add(bars + 0, 1u, __ATOMIC_ACQ_REL, __HIP_MEMORY_SCOPE_AGENT);
    while (__hip_atomic_load(bars + 0, __ATOMIC_ACQUIRE, __HIP_MEMORY_SCOPE_AGENT) < 512u)
      __builtin_amdgcn_s_sleep(32);
    __threadfence();  // acquire: invalidate stale caches before x3 reads
  }
  __syncthreads();

  // ---- convf: 1x1 conv (128->1) + bias + clip + rowmax; blocks 0..127, row y = b ----
  if (b < 128) {
    float* fpart = wlds;  // reuse 256 floats of LDS
    int y = b;
    int pt = tid >> 7;  // 2 partials of 64 ci each
    float facc = 0.f;
    const float* ip = x3 + y * 128 + X;
    for (int ci = pt * 64; ci < pt * 64 + 64; ++ci) facc += ip[ci * 16384] * wf[ci];
    fpart[tid] = facc;
    __syncthreads();
    if (tid < 128) {
      float s = fpart[tid] + fpart[tid + 128] + bfp[0];
      fpart[tid] = fminf(fmaxf(s, -1.f), 1.f);
    }
    __syncthreads();
    if (tid < 64) {
      float m = fmaxf(fpart[tid], fpart[tid + 64]);
      for (int off = 32; off; off >>= 1) m = fmaxf(m, __shfl_down(m, off, 64));
      if (tid == 0) rowm[y] = m;
    }
    // ---- last-arriving convf block computes the final mean ----
    __syncthreads();
    if (tid == 0) {
      __threadfence();  // release rowm[y]
      unsigned int old = __hip_atomic_fetch_add(bars + 1, 1u, __ATOMIC_ACQ_REL,
                                                __HIP_MEMORY_SCOPE_AGENT);
      lastf = (old == 127u) ? 1u : 0u;
      if (lastf) __threadfence();  // acquire before reading others' rowm
    }
    __syncthreads();
    if (lastf) {
      float* red = wlds;
      float v = (tid < 128) ? rowm[tid] : 0.f;
      for (int off = 32; off; off >>= 1) v += __shfl_down(v, off, 64);
      if (tid < 128 && (tid & 63) == 0) red[tid >> 6] = v;
      __syncthreads();
      if (tid == 0) out[0] = (red[0] + red[1]) * (1.f / 128.f);
    }
  }
}

extern "C" void kernel_launch(void* const* d_in, const int* in_sizes, int n_in,
                              void* d_out, int out_size, void* d_ws, size_t ws_size,
                              hipStream_t stream) {
  const float* q  = (const float*)d_in[0];
  const float* t  = (const float*)d_in[1];
  const float* w1 = (const float*)d_in[2];
  const float* b1 = (const float*)d_in[3];
  const float* w2 = (const float*)d_in[4];
  const float* b2 = (const float*)d_in[5];
  const float* w3 = (const float*)d_in[6];
  const float* b3 = (const float*)d_in[7];
  const float* wf = (const float*)d_in[8];
  const float* bf = (const float*)d_in[9];
  float* out = (float*)d_out;
  char* ws = (char*)d_ws;

  unsigned char* qf8 = (unsigned char*)(ws + 0);          // 17,694,720
  unsigned char* tf8 = (unsigned char*)(ws + 17694720);   // 17,694,720
  float* f2f  = (float*)(ws + 44826624);                  // 512x512
  float* x1   = (float*)(ws + 45875200);                  // 32x256x256
  float* x2b  = (float*)(ws + 54263808);                  // 64x128x128
  float* x3   = (float*)(ws + 58458112);                  // 128x128x128
  float* rowm = (float*)(ws + 66846720);                  // 128 floats
  unsigned int* bars = (unsigned int*)(ws + 66847232);    // 2 barrier counters

  hipMemsetAsync(bars, 0, 16, stream);  // re-zero counters each graph replay
  cvt_fp8_kernel<<<8640, 256, 0, stream>>>(q, t, (unsigned int*)qf8, (unsigned int*)tf8);
  gemm_cmax_kernel<<<256, 768, 0, stream>>>(qf8, tf8, f2f);
  conv1_kernel<<<1024, 256, 0, stream>>>(f2f, w1, b1, x1);
  conv2_kernel<<<512, 256, 0, stream>>>(x1, w2, b2, x2b);
  conv3f_kernel<<<512, 256, 0, stream>>>(x2b, w3, b3, wf, bf, x3, rowm, bars, out);
}

// Round 9
// 383.613 us; speedup vs baseline: 1.4228x; 1.2048x over previous
//
#include <hip/hip_runtime.h>
#include <hip/hip_bf16.h>

typedef float f32x4 __attribute__((ext_vector_type(4)));
typedef int v8i __attribute__((ext_vector_type(8)));

#define AS3 __attribute__((address_space(3)))
#define AS1 __attribute__((address_space(1)))

// ---------------- fp32 -> fp8 e4m3 (OCP) conversion with x16 scale (q and t fused) ----------------
// Both sides ideally coalesced via 4KB LDS transpose:
//   loads:  4x float4/thread, wave-contiguous 1KB per instruction
//   stores: uint4/thread (16B/lane), wave-contiguous 1KB per instruction
// (R2 version had 4B/lane stores; cvt inferred ~100+ us from R6/R8 accounting, 4x roofline.)
__global__ __launch_bounds__(256) void cvt_fp8_kernel(const float* __restrict__ q,
                                                      const float* __restrict__ t,
                                                      uint4* __restrict__ qd,
                                                      uint4* __restrict__ td) {
  __shared__ unsigned int lds[1024];
  int b = blockIdx.x;  // 8640 blocks: 4320 per matrix, 1024 float4 per block
  const float4* s4;
  uint4* dst4;
  int base;
  if (b < 4320) { s4 = (const float4*)q; dst4 = qd; base = b * 1024; }
  else          { s4 = (const float4*)t; dst4 = td; base = (b - 4320) * 1024; }
  int tid = threadIdx.x;
#pragma unroll
  for (int k = 0; k < 4; ++k) {
    float4 v = s4[base + k * 256 + tid];
    int w = 0;
    w = __builtin_amdgcn_cvt_pk_fp8_f32(v.x * 16.f, v.y * 16.f, w, false);
    w = __builtin_amdgcn_cvt_pk_fp8_f32(v.z * 16.f, v.w * 16.f, w, true);
    lds[k * 256 + tid] = w;
  }
  __syncthreads();
  uint4 o = *(const uint4*)&lds[tid * 4];
  dst4[(base >> 2) + tid] = o;
}

// ---------------- fused GEMM (MX fp8, K=128) + max over p + mean over o -> f2f[512][512] ----------------
// R4 version (unchanged, proven 122.8 us): R1 loop + in-block o-mean epilogue.
__global__ __launch_bounds__(768) void gemm_cmax_kernel(const unsigned char* __restrict__ qf8,
                                                        const unsigned char* __restrict__ tf8,
                                                        float* __restrict__ f2f) {
  __shared__ __align__(16) char smem[147456];
  const int tid  = threadIdx.x;
  const int wv   = tid >> 6;
  const int lane = tid & 63;
  const int quad = lane >> 4;
  const int l16  = lane & 15;
  const int wrow = wv >> 1, wcol = wv & 1;
  const int x = blockIdx.x & 7, r = blockIdx.x >> 3;
  const int bi = (x >> 1) * 4 + (r & 3);
  const int bj = (x & 1) * 8 + (r >> 2);

  f32x4 acc[3][9];
#pragma unroll
  for (int a = 0; a < 3; ++a)
#pragma unroll
    for (int b = 0; b < 9; ++b) acc[a][b] = (f32x4){0.f, 0.f, 0.f, 0.f};

  const unsigned char* gptr[6];
#pragma unroll
  for (int i = 0; i < 6; ++i) {
    int s   = i * 768 + wv * 64 + lane;
    int mat = (s >= 2304);
    int sm  = s - mat * 2304;
    int row = sm >> 3, pc = sm & 7;
    int gc  = pc ^ (row & 7);
    const unsigned char* base = mat ? (tf8 + (size_t)(bj * 288 + row) * 3840)
                                    : (qf8 + (size_t)(bi * 288 + row) * 3840);
    gptr[i] = base + gc * 16;
  }

  int buf = 0;
#pragma unroll
  for (int i = 0; i < 6; ++i)
    __builtin_amdgcn_global_load_lds((const AS1 void*)(gptr[i]),
                                     (AS3 void*)(smem + (i * 768 + wv * 64) * 16), 16, 0, 0);

  const int arow0 = wrow * 48 + l16;
  const int bcol0 = wcol * 144 + l16;

  for (int kt = 0; kt < 30; ++kt) {
    __syncthreads();
    if (kt < 29) {
      int nb = buf ^ 1;
#pragma unroll
      for (int i = 0; i < 6; ++i)
        __builtin_amdgcn_global_load_lds((const AS1 void*)(gptr[i] + (kt + 1) * 128),
                                         (AS3 void*)(smem + nb * 73728 + (i * 768 + wv * 64) * 16),
                                         16, 0, 0);
    }
    const char* A = smem + buf * 73728;
    const char* B = A + 36864;

    v8i av[3];
#pragma unroll
    for (int sr = 0; sr < 3; ++sr) {
      int row = arow0 + sr * 16;
      int sw  = row & 7;
      int p0  = (quad * 2) ^ sw, p1 = (quad * 2 + 1) ^ sw;
      int4 lo = *(const int4*)(A + row * 128 + p0 * 16);
      int4 hi = *(const int4*)(A + row * 128 + p1 * 16);
      v8i v;
      v[0] = lo.x; v[1] = lo.y; v[2] = lo.z; v[3] = lo.w;
      v[4] = hi.x; v[5] = hi.y; v[6] = hi.z; v[7] = hi.w;
      av[sr] = v;
    }
#pragma unroll
    for (int c = 0; c < 9; ++c) {
      int col = bcol0 + c * 16;
      int sw  = col & 7;
      int p0  = (quad * 2) ^ sw, p1 = (quad * 2 + 1) ^ sw;
      int4 lo = *(const int4*)(B + col * 128 + p0 * 16);
      int4 hi = *(const int4*)(B + col * 128 + p1 * 16);
      v8i bv;
      bv[0] = lo.x; bv[1] = lo.y; bv[2] = lo.z; bv[3] = lo.w;
      bv[4] = hi.x; bv[5] = hi.y; bv[6] = hi.z; bv[7] = hi.w;
      acc[0][c] = __builtin_amdgcn_mfma_scale_f32_16x16x128_f8f6f4(
          av[0], bv, acc[0][c], 0, 0, 0, 0x7f7f7f7f, 0, 0x7f7f7f7f);
      acc[1][c] = __builtin_amdgcn_mfma_scale_f32_16x16x128_f8f6f4(
          av[1], bv, acc[1][c], 0, 0, 0, 0x7f7f7f7f, 0, 0x7f7f7f7f);
      acc[2][c] = __builtin_amdgcn_mfma_scale_f32_16x16x128_f8f6f4(
          av[2], bv, acc[2][c], 0, 0, 0, 0x7f7f7f7f, 0, 0x7f7f7f7f);
    }
    buf ^= 1;
  }

  __syncthreads();
  float* scr  = (float*)smem;                  // [16][288]
  float* mbuf = (float*)(smem + 18432);        // [288][33]
#pragma unroll
  for (int b = 0; b < 18; ++b) {
    const int bw = b / 3, bs = b - bw * 3;
    if (wrow == bw) {
#pragma unroll
      for (int c = 0; c < 9; ++c)
#pragma unroll
        for (int rr = 0; rr < 4; ++rr)
          scr[(quad * 4 + rr) * 288 + wcol * 144 + c * 16 + l16] = acc[bs][c][rr] * (1.f / 256.f);
    }
    __syncthreads();
    if (tid < 512) {
      int row = tid >> 5, jg = tid & 31;
      const float* p = scr + row * 288 + jg * 9;
      float m = p[0];
#pragma unroll
      for (int k = 1; k < 9; ++k) m = fmaxf(m, p[k]);
      mbuf[(b * 16 + row) * 33 + jg] = m;
    }
    __syncthreads();
  }
  for (int p = tid; p < 1024; p += 768) {
    int il = p >> 5, jg = p & 31;
    const float* mp = mbuf + (il * 9) * 33 + jg;
    float s = 0.f;
#pragma unroll
    for (int o = 0; o < 9; ++o) s += mp[o * 33];
    f2f[(size_t)(bi * 32 + il) * 512 + bj * 32 + jg] = s * (1.f / 9.f);
  }
}

// ---------------- conv1: 1->32ch 3x3 same + relu + 2x2 maxpool, 512^2 -> 256^2 ----------------
// R4-proven (1024 blocks, 4 chg x 8 ch).
__global__ __launch_bounds__(256) void conv1_kernel(const float* __restrict__ in,
                                                    const float* __restrict__ w1,
                                                    const float* __restrict__ b1,
                                                    float* __restrict__ out) {
  __shared__ float tile[34 * 36];
  __shared__ float wl[320];
  int t = blockIdx.x & 255;
  int chg = blockIdx.x >> 8;
  int ty0 = (t >> 4) * 32, tx0 = (t & 15) * 32;
  int py = threadIdx.x >> 4, px = threadIdx.x & 15;

  for (int idx = threadIdx.x; idx < 320; idx += 256)
    wl[idx] = (idx < 288) ? w1[idx] : b1[idx - 288];
  for (int idx = threadIdx.x; idx < 34 * 34; idx += 256) {
    int r = idx / 34, c = idx % 34;
    int gy = ty0 + r - 1, gx = tx0 + c - 1;
    tile[r * 36 + c] = ((unsigned)gy < 512u && (unsigned)gx < 512u) ? in[gy * 512 + gx] : 0.f;
  }
  __syncthreads();

  float win[4][4];
#pragma unroll
  for (int r = 0; r < 4; ++r)
#pragma unroll
    for (int c = 0; c < 4; ++c)
      win[r][c] = tile[(2 * py + r) * 36 + 2 * px + c];

  int gy2 = (t >> 4) * 16 + py, gx2 = (t & 15) * 16 + px;
  int ch0 = chg * 8;
  for (int ch = ch0; ch < ch0 + 8; ++ch) {
    float w[9];
#pragma unroll
    for (int k = 0; k < 9; ++k) w[k] = wl[ch * 9 + k];
    float m = -INFINITY;
#pragma unroll
    for (int a = 0; a < 2; ++a)
#pragma unroll
      for (int b = 0; b < 2; ++b) {
        float s = 0.f;
#pragma unroll
        for (int ky = 0; ky < 3; ++ky)
#pragma unroll
          for (int kx = 0; kx < 3; ++kx) s += win[a + ky][b + kx] * w[ky * 3 + kx];
        m = fmaxf(m, s);
      }
    out[ch * 65536 + gy2 * 256 + gx2] = fmaxf(m + wl[288 + ch], 0.f);
  }
}

// ---------------- conv2: 32->64ch 3x3 same + relu + 2x2 maxpool, 256^2 -> 128^2 ----------------
// R4-proven (512 blocks = 32 stripes x 16 cog).
__global__ __launch_bounds__(256) void conv2_kernel(const float* __restrict__ in,
                                                    const float* __restrict__ w2,
                                                    const float* __restrict__ b2,
                                                    float* __restrict__ out) {
  __shared__ __align__(16) float wlds[32 * 4 * 12];        // 6144 B
  __shared__ __align__(16) float tile[2 * 2 * 10 * 264];   // 42240 B
  const int tid = threadIdx.x;
  const int stripe = blockIdx.x & 31, cog = blockIdx.x >> 5;
  const int X = tid;
  const int Y0 = stripe * 8;

  for (int idx = tid; idx < 1152; idx += 256) {
    int co = idx / 288, rem = idx % 288, ci = rem / 9, k = rem % 9;
    wlds[(ci * 4 + co) * 12 + k] = w2[((cog * 4 + co) * 32 + ci) * 9 + k];
  }
  if (tid < 80) {
    int bu = tid / 40, rem = tid % 40, pl = rem / 20, r2 = rem % 20;
    int rr = r2 >> 1, side = r2 & 1;
    tile[bu * 5280 + pl * 2640 + rr * 264 + (side ? 260 : 3)] = 0.f;
  }
  int gof[5], lof[5];
#pragma unroll
  for (int i = 0; i < 5; ++i) {
    int idx = tid + i * 256;
    int rw = idx >> 6, c4 = idx & 63;
    int pl = (rw >= 10), rr = rw - pl * 10;
    int gy = Y0 + rr - 1;
    lof[i] = pl * 2640 + rr * 264 + 4 + c4 * 4;
    gof[i] = ((unsigned)gy < 256u) ? (pl * 65536 + gy * 256 + c4 * 4) : -1;
  }
#pragma unroll
  for (int i = 0; i < 5; ++i) {
    float4 v = (gof[i] >= 0) ? *(const float4*)(in + gof[i]) : (float4){0, 0, 0, 0};
    *(float4*)&tile[lof[i]] = v;
  }
  __syncthreads();

  float acc[8][4];
#pragma unroll
  for (int y = 0; y < 8; ++y)
#pragma unroll
    for (int co = 0; co < 4; ++co) acc[y][co] = 0.f;

#pragma unroll 1
  for (int cb = 0; cb < 16; ++cb) {
    int buf = cb & 1;
    float4 pf[5];
    if (cb < 15) {
#pragma unroll
      for (int i = 0; i < 5; ++i)
        pf[i] = (gof[i] >= 0) ? *(const float4*)(in + gof[i] + (cb + 1) * 131072)
                              : (float4){0, 0, 0, 0};
    }
    const float* tb = tile + buf * 5280;
#pragma unroll
    for (int pl = 0; pl < 2; ++pl) {
      const float* tp = tb + pl * 2640;
      int ci = cb * 2 + pl;
      float w[4][9];
#pragma unroll
      for (int co = 0; co < 4; ++co) {
        const float* wp = &wlds[(ci * 4 + co) * 12];
        float4 w0 = *(const float4*)wp;
        float4 w1v = *(const float4*)(wp + 4);
        w[co][0] = w0.x; w[co][1] = w0.y; w[co][2] = w0.z; w[co][3] = w0.w;
        w[co][4] = w1v.x; w[co][5] = w1v.y; w[co][6] = w1v.z; w[co][7] = w1v.w;
        w[co][8] = wp[8];
      }
      float r0[3], r1[3], r2[3];
      const float* p0 = tp + X + 3;
      r0[0] = p0[0]; r0[1] = p0[1]; r0[2] = p0[2];
      const float* p1 = tp + 264 + X + 3;
      r1[0] = p1[0]; r1[1] = p1[1]; r1[2] = p1[2];
#pragma unroll
      for (int y = 0; y < 8; ++y) {
        const float* p2 = tp + (y + 2) * 264 + X + 3;
        r2[0] = p2[0]; r2[1] = p2[1]; r2[2] = p2[2];
#pragma unroll
        for (int co = 0; co < 4; ++co)
          acc[y][co] += r0[0] * w[co][0] + r0[1] * w[co][1] + r0[2] * w[co][2]
                      + r1[0] * w[co][3] + r1[1] * w[co][4] + r1[2] * w[co][5]
                      + r2[0] * w[co][6] + r2[1] * w[co][7] + r2[2] * w[co][8];
        r0[0] = r1[0]; r0[1] = r1[1]; r0[2] = r1[2];
        r1[0] = r2[0]; r1[1] = r2[1]; r1[2] = r2[2];
      }
    }
    if (cb < 15) {
#pragma unroll
      for (int i = 0; i < 5; ++i)
        *(float4*)&tile[(buf ^ 1) * 5280 + lof[i]] = pf[i];
    }
    __syncthreads();
  }

  int x2 = X >> 1;
#pragma unroll
  for (int co = 0; co < 4; ++co) {
    float bias = b2[cog * 4 + co];
#pragma unroll
    for (int y2 = 0; y2 < 4; ++y2) {
      float v = fmaxf(acc[2 * y2][co], acc[2 * y2 + 1][co]);
      v = fmaxf(v + bias, 0.f);
      float o = fmaxf(v, __shfl_xor(v, 1, 64));
      if ((X & 1) == 0)
        out[(cog * 4 + co) * 16384 + (stripe * 4 + y2) * 128 + x2] = o;
    }
  }
}

// ---------------- conv3: 64->128ch 3x3 same + relu, 128^2 ----------------
// R4-proven (512 blocks = 8 stripes x 64 cog, 2 co each).
__global__ __launch_bounds__(256) void conv3_kernel(const float* __restrict__ in,
                                                    const float* __restrict__ w3,
                                                    const float* __restrict__ b3,
                                                    float* __restrict__ out) {
  __shared__ __align__(16) float wlds[64 * 2 * 12];       // 6144 B
  __shared__ __align__(16) float tile[2 * 2 * 18 * 136];  // 39168 B
  const int tid = threadIdx.x;
  const int stripe = blockIdx.x & 7, cog = blockIdx.x >> 3;
  const int X = tid & 127, yh = tid >> 7;
  const int Y0 = stripe * 16;

  for (int idx = tid; idx < 1152; idx += 256) {
    int co = idx / 576, rem = idx % 576, ci = rem / 9, k = rem % 9;
    wlds[(ci * 2 + co) * 12 + k] = w3[((cog * 2 + co) * 64 + ci) * 9 + k];
  }
  if (tid < 144) {
    int bu = tid / 72, rem = tid % 72, pl = rem / 36, r2 = rem % 36;
    int rr = r2 >> 1, side = r2 & 1;
    tile[bu * 4896 + pl * 2448 + rr * 136 + (side ? 132 : 3)] = 0.f;
  }
  int gof[5], lof[5];
#pragma unroll
  for (int i = 0; i < 5; ++i) {
    int idx = tid + i * 256;
    if (idx < 1152) {
      int rw = idx >> 5, c4 = idx & 31;
      int pl = (rw >= 18), rr = rw - pl * 18;
      int gy = Y0 + rr - 1;
      lof[i] = pl * 2448 + rr * 136 + 4 + c4 * 4;
      gof[i] = ((unsigned)gy < 128u) ? (pl * 16384 + gy * 128 + c4 * 4) : -1;
    } else { lof[i] = -1; gof[i] = -1; }
  }
#pragma unroll
  for (int i = 0; i < 5; ++i)
    if (lof[i] >= 0) {
      float4 v = (gof[i] >= 0) ? *(const float4*)(in + gof[i]) : (float4){0, 0, 0, 0};
      *(float4*)&tile[lof[i]] = v;
    }
  __syncthreads();

  float acc[8][2];
#pragma unroll
  for (int y = 0; y < 8; ++y)
#pragma unroll
    for (int co = 0; co < 2; ++co) acc[y][co] = 0.f;

#pragma unroll 1
  for (int cb = 0; cb < 32; ++cb) {
    int buf = cb & 1;
    float4 pf[5];
    if (cb < 31) {
#pragma unroll
      for (int i = 0; i < 5; ++i)
        pf[i] = (gof[i] >= 0) ? *(const float4*)(in + gof[i] + (cb + 1) * 32768)
                              : (float4){0, 0, 0, 0};
    }
    const float* tb = tile + buf * 4896;
#pragma unroll
    for (int pl = 0; pl < 2; ++pl) {
      const float* tp = tb + pl * 2448;
      int ci = cb * 2 + pl;
      float w[2][9];
#pragma unroll
      for (int co = 0; co < 2; ++co) {
        const float* wp = &wlds[(ci * 2 + co) * 12];
        float4 w0 = *(const float4*)wp;
        float4 w1v = *(const float4*)(wp + 4);
        w[co][0] = w0.x; w[co][1] = w0.y; w[co][2] = w0.z; w[co][3] = w0.w;
        w[co][4] = w1v.x; w[co][5] = w1v.y; w[co][6] = w1v.z; w[co][7] = w1v.w;
        w[co][8] = wp[8];
      }
      float r0[3], r1[3], r2[3];
      const float* p0 = tp + (yh * 8) * 136 + X + 3;
      r0[0] = p0[0]; r0[1] = p0[1]; r0[2] = p0[2];
      const float* p1 = tp + (yh * 8 + 1) * 136 + X + 3;
      r1[0] = p1[0]; r1[1] = p1[1]; r1[2] = p1[2];
#pragma unroll
      for (int y = 0; y < 8; ++y) {
        const float* p2 = tp + (yh * 8 + y + 2) * 136 + X + 3;
        r2[0] = p2[0]; r2[1] = p2[1]; r2[2] = p2[2];
#pragma unroll
        for (int co = 0; co < 2; ++co)
          acc[y][co] += r0[0] * w[co][0] + r0[1] * w[co][1] + r0[2] * w[co][2]
                      + r1[0] * w[co][3] + r1[1] * w[co][4] + r1[2] * w[co][5]
                      + r2[0] * w[co][6] + r2[1] * w[co][7] + r2[2] * w[co][8];
        r0[0] = r1[0]; r0[1] = r1[1]; r0[2] = r1[2];
        r1[0] = r2[0]; r1[1] = r2[1]; r1[2] = r2[2];
      }
    }
    if (cb < 31) {
#pragma unroll
      for (int i = 0; i < 5; ++i)
        if (lof[i] >= 0) *(float4*)&tile[(buf ^ 1) * 4896 + lof[i]] = pf[i];
    }
    __syncthreads();
  }

#pragma unroll
  for (int co = 0; co < 2; ++co) {
    float bias = b3[cog * 2 + co];
    float* op = out + (cog * 2 + co) * 16384 + (Y0 + yh * 8) * 128 + X;
#pragma unroll
    for (int y = 0; y < 8; ++y)
      op[y * 128] = fmaxf(acc[y][co] + bias, 0.f);
  }
}

// ---------------- 1x1 conv (128->1) + bias + clip + rowmax over x ----------------
__global__ __launch_bounds__(512) void convf_kernel(const float* __restrict__ in,
                                                    const float* __restrict__ wf,
                                                    const float* __restrict__ bfp,
                                                    float* __restrict__ rowm) {
  __shared__ float part[512];
  int y = blockIdx.x, tid = threadIdx.x;
  int pt = tid >> 7, x = tid & 127;
  float acc = 0.f;
  const float* ip = in + y * 128 + x;
  for (int ci = pt * 32; ci < pt * 32 + 32; ++ci) acc += ip[ci * 16384] * wf[ci];
  part[tid] = acc;
  __syncthreads();
  if (tid < 128) {
    float s = part[tid] + part[tid + 128] + part[tid + 256] + part[tid + 384] + bfp[0];
    part[tid] = fminf(fmaxf(s, -1.f), 1.f);
  }
  __syncthreads();
  if (tid < 64) {
    float m = fmaxf(part[tid], part[tid + 64]);
    for (int off = 32; off; off >>= 1) m = fmaxf(m, __shfl_down(m, off, 64));
    if (tid == 0) rowm[y] = m;
  }
}

// ---------------- mean over rows -> scalar ----------------
__global__ __launch_bounds__(128) void final_kernel(const float* __restrict__ rowm,
                                                    float* __restrict__ out) {
  int x = threadIdx.x;
  float v = rowm[x];
  for (int off = 32; off; off >>= 1) v += __shfl_down(v, off, 64);
  __shared__ float red[2];
  if ((x & 63) == 0) red[x >> 6] = v;
  __syncthreads();
  if (x == 0) out[0] = (red[0] + red[1]) * (1.f / 128.f);
}

extern "C" void kernel_launch(void* const* d_in, const int* in_sizes, int n_in,
                              void* d_out, int out_size, void* d_ws, size_t ws_size,
                              hipStream_t stream) {
  const float* q  = (const float*)d_in[0];
  const float* t  = (const float*)d_in[1];
  const float* w1 = (const float*)d_in[2];
  const float* b1 = (const float*)d_in[3];
  const float* w2 = (const float*)d_in[4];
  const float* b2 = (const float*)d_in[5];
  const float* w3 = (const float*)d_in[6];
  const float* b3 = (const float*)d_in[7];
  const float* wf = (const float*)d_in[8];
  const float* bf = (const float*)d_in[9];
  float* out = (float*)d_out;
  char* ws = (char*)d_ws;

  unsigned char* qf8 = (unsigned char*)(ws + 0);          // 17,694,720
  unsigned char* tf8 = (unsigned char*)(ws + 17694720);   // 17,694,720
  float* f2f  = (float*)(ws + 44826624);                  // 512x512
  float* x1   = (float*)(ws + 45875200);                  // 32x256x256
  float* x2b  = (float*)(ws + 54263808);                  // 64x128x128
  float* x3   = (float*)(ws + 58458112);                  // 128x128x128
  float* rowm = (float*)(ws + 66846720);                  // 128

  cvt_fp8_kernel<<<8640, 256, 0, stream>>>(q, t, (uint4*)qf8, (uint4*)tf8);
  gemm_cmax_kernel<<<256, 768, 0, stream>>>(qf8, tf8, f2f);
  conv1_kernel<<<1024, 256, 0, stream>>>(f2f, w1, b1, x1);
  conv2_kernel<<<512, 256, 0, stream>>>(x1, w2, b2, x2b);
  conv3_kernel<<<512, 256, 0, stream>>>(x2b, w3, b3, x3);
  convf_kernel<<<128, 512, 0, stream>>>(x3, wf, bf, rowm);
  final_kernel<<<1, 128, 0, stream>>>(rowm, out);
}